// Round 10
// baseline (311.142 us; speedup 1.0000x reference)
//
#include <hip/hip_runtime.h>
#include <math.h>

typedef _Float16 half_t;
typedef __attribute__((ext_vector_type(8))) _Float16 half8;
typedef __attribute__((ext_vector_type(4))) _Float16 half4;
typedef __attribute__((ext_vector_type(4))) float floatx4;

#define TDIM 36
#define PDIM 161        // 2*80+1 atoms
#define NCOL 50
#define DHALF 25        // columns per block (d split across 2 blocks per batch item)
#define NITER 100
#define PITER8 50       // power steps on G^8 == 400 on G (proven config)

// R8 per-wave structure, split into 2 blocks/CU for barrier desync.
// Grid: 512 blocks x 384 threads (6 waves). block = (batch b, column-half dh).
// phase A: M=48,N=32,K=192 (6 ks), 6 waves = 3 mt x 2 nt, D hi/lo (12 MFMA/wave)
// phase B: M=192 (12 pt incl ghost pt=11), N=32, K=64; wave g owns pt {g,g+6},
//          both stripes; D^T hi ONLY -> 8 MFMA/wave.
// R9 LESSON: __launch_bounds__(384,4) capped VGPR at 64 -> fragment spill ->
// 86 MB scratch traffic. Use (384,2): budget 256, compiler takes ~80-96, no
// spill; HW residency from actual usage = 16-wave step -> 2 blocks/CU desynced.
#define NKA 6
#define GSTR 44
#define SPS 196         // Df (fp32) row stride (dwords)

// row strides in BYTES
#define YROW 384        // y^T [32][192] half
#define RROW 128        // R^T [32][64] half

// XOR swizzle: spread same-column reads across 8 rows -> 8 distinct 16B slots
#define SWZ(row, byteoff) ((byteoff) ^ (((row) & 7) << 4))

// ---- byte-offset LDS map: 48,544 B per block -> 2 blocks/CU (97 KB) ----
#define BY_Y    0                      // 12,288
#define BY_R    12288                  //  4,096
#define BY_DFX  16384                  // 11,840 (Df tail spill: Df = 28,224 B total)
#define BY_LRTH 28224                  //  1,288
#define BY_SC   29512                  //     16
#define BY_GS   29536                  //  6,336 (16B aligned)
#define BY_G2   35872                  //  6,336 (holds G^2, later G^8)
#define BY_G4   42208                  //  6,336
#define LDS_TOTAL 48544
// setup alias: Df fp32 [36][196] = 28,224 B over Y+R+DFX (Y+R re-zeroed before loop)

#define MFMA16 __builtin_amdgcn_mfma_f32_16x16x32_f16

__global__ __launch_bounds__(384, 2)
void dan_kernel(const float* __restrict__ xin, const float* __restrict__ rho,
                const float* __restrict__ theta, float* __restrict__ outC,
                float* __restrict__ outDic, float* __restrict__ outR)
{
  extern __shared__ char smc[];
  float*  sc   = (float*)(smc + BY_SC);
  float*  Gs   = (float*)(smc + BY_GS);
  float*  G2   = (float*)(smc + BY_G2);
  float*  G4   = (float*)(smc + BY_G4);
  float*  Df   = (float*)(smc + BY_Y);    // setup alias (28,224 B)
  float*  lrth = (float*)(smc + BY_LRTH); // [161] lr, [161] th (setup only)

  const int tid = threadIdx.x;
  const int blk = blockIdx.x;
  const int b  = blk >> 1;              // batch item
  const int dh = blk & 1;               // column half: cols dh*25 .. dh*25+24
  const int wave = tid >> 6, lane = tid & 63;
  const int q = lane >> 4, ln = lane & 15;

  // ---- A. zero all LDS (pads must be 0)
  {
    unsigned int* z = (unsigned int*)smc;
    for (int i = tid; i < LDS_TOTAL / 4; i += 384) z[i] = 0u;
  }
  __syncthreads();

  // ---- B0. per-atom lr/th (161 threads, 2 transcendentals each)
  if (tid >= 1 && tid < PDIM) {
    const bool is_sin = tid > 80;
    const int n = is_sin ? (tid - 81) : (tid - 1);
    lrth[tid]       = logf(0.001f + 1.149f / (1.0f + expf(-rho[n])));
    lrth[161 + tid] = 3.14159265358979f / (1.0f + expf(-theta[n]));
  }
  __syncthreads();

  // ---- B1. raw dictionary, parallel over all (t,p) jobs
  for (int i = tid; i < TDIM * PDIM; i += 384) {
    const int t = i / PDIM, p = i - t * PDIM;
    float val;
    if (p == 0) {
      val = 1.0f;
    } else {
      const float ft = (float)t;
      const float e = expf(ft * lrth[p]);
      const float ang = ft * lrth[161 + p];
      val = e * (p > 80 ? sinf(ang) : cosf(ang));
    }
    Df[t * SPS + p] = val;
  }
  __syncthreads();

  // ---- B2. column-normalize (atoms 1..160)
  if (tid >= 1 && tid < PDIM) {
    float s2 = 0.0f;
    for (int t = 0; t < TDIM; ++t) {
      const float v = Df[t * SPS + tid];
      s2 += v * v;
    }
    const float inv = 1.0f / sqrtf(s2);
    for (int t = 0; t < TDIM; ++t) Df[t * SPS + tid] *= inv;
  }
  __syncthreads();

  // ---- C. Gram -> Gs ; dic out ; load ALL MFMA fragments to registers
  for (int job = tid; job < 666; job += 384) {   // 666 = 36*37/2
    int i = 0, rem = job;
    while (rem >= TDIM - i) { rem -= TDIM - i; ++i; }
    const int j = i + rem;
    const float4* ri = (const float4*)(Df + i * SPS);
    const float4* rj = (const float4*)(Df + j * SPS);
    float a = 0.0f;
    #pragma unroll 7
    for (int k = 0; k < SPS / 4; ++k) {
      const float4 x = ri[k], y = rj[k];
      a += x.x * y.x + x.y * y.y + x.z * y.z + x.w * y.w;
    }
    Gs[i * GSTR + j] = a;
    Gs[j * GSTR + i] = a;
  }
  if (blk == 0) {
    for (int i = tid; i < TDIM * PDIM; i += 384) {
      const int t = i / PDIM, p = i - t * PDIM;
      outDic[i] = Df[t * SPS + p];
    }
  }

  // ownership maps
  const int mtA = wave >> 1;            // phase A: 3 mt x 2 nt, one tile per wave
  const int ntA = wave & 1;
  const int g = wave;                   // phase B: pt in {g, g+6}; both stripes

  // phase-A A-fragments (D hi/lo); rows >= 36 are zero
  half8 DhF[NKA], DlF[NKA];
  {
    const int row = 16 * mtA + ln;
    #pragma unroll
    for (int ks = 0; ks < NKA; ++ks) {
      half8 hh = {0,0,0,0,0,0,0,0}, ll = {0,0,0,0,0,0,0,0};
      if (row < TDIM) {
        const float4 f0 = *(const float4*)(Df + row * SPS + 32 * ks + 8 * q);
        const float4 f1 = *(const float4*)(Df + row * SPS + 32 * ks + 8 * q + 4);
        const float fa[8] = {f0.x, f0.y, f0.z, f0.w, f1.x, f1.y, f1.z, f1.w};
        #pragma unroll
        for (int e = 0; e < 8; ++e) {
          const half_t h2 = (half_t)fa[e];
          hh[e] = h2;
          ll[e] = (half_t)(fa[e] - (float)h2);
        }
      }
      DhF[ks] = hh;
      DlF[ks] = ll;
    }
  }
  // phase-B A-fragments (D^T hi ONLY); atoms >= 161 are zero cols of Df
  half8 DtH[2][2];                      // [k][ks]
  #pragma unroll
  for (int k = 0; k < 2; ++k) {
    const int atom = 16 * (g + 6 * k) + ln;         // 0..191
    #pragma unroll
    for (int ks = 0; ks < 2; ++ks) {
      half8 hh;
      #pragma unroll
      for (int e = 0; e < 8; ++e) {
        const int t = 32 * ks + 8 * q + e;
        const float v = (t < TDIM) ? Df[t * SPS + atom] : 0.0f;
        hh[e] = (half_t)v;
      }
      DtH[k][ks] = hh;
    }
  }
  // static Y (fp32) at phase-A C positions (this block's 25-column half)
  float yA[4];
  {
    const float* xb = xin + b * TDIM * NCOL;
    const int c = 16 * ntA + ln;        // 0..31 local
    #pragma unroll
    for (int r = 0; r < 4; ++r) {
      const int t = 16 * mtA + 4 * q + r;
      yA[r] = (t < TDIM && c < DHALF) ? xb[t * NCOL + dh * DHALF + c] : 0.0f;
    }
  }
  __syncthreads();

  // ---- C2. G2 = G*G  (pads of all Gram buffers are zero)
  for (int job = tid; job < 666; job += 384) {
    int i = 0, rem = job;
    while (rem >= TDIM - i) { rem -= TDIM - i; ++i; }
    const int j = i + rem;
    const float4* ri = (const float4*)(Gs + i * GSTR);
    const float4* rj = (const float4*)(Gs + j * GSTR);
    float a = 0.0f;
    #pragma unroll
    for (int k = 0; k < GSTR / 4; ++k) {
      const float4 x = ri[k], y = rj[k];
      a += x.x * y.x + x.y * y.y + x.z * y.z + x.w * y.w;
    }
    G2[i * GSTR + j] = a;
    G2[j * GSTR + i] = a;
  }
  __syncthreads();
  // ---- C3. G4 = G2*G2
  for (int job = tid; job < 666; job += 384) {
    int i = 0, rem = job;
    while (rem >= TDIM - i) { rem -= TDIM - i; ++i; }
    const int j = i + rem;
    const float4* ri = (const float4*)(G2 + i * GSTR);
    const float4* rj = (const float4*)(G2 + j * GSTR);
    float a = 0.0f;
    #pragma unroll
    for (int k = 0; k < GSTR / 4; ++k) {
      const float4 x = ri[k], y = rj[k];
      a += x.x * y.x + x.y * y.y + x.z * y.z + x.w * y.w;
    }
    G4[i * GSTR + j] = a;
    G4[j * GSTR + i] = a;
  }
  __syncthreads();
  // ---- C4. G8 = G4*G4 -> overwrite G2 buffer
  for (int job = tid; job < 666; job += 384) {
    int i = 0, rem = job;
    while (rem >= TDIM - i) { rem -= TDIM - i; ++i; }
    const int j = i + rem;
    const float4* ri = (const float4*)(G4 + i * GSTR);
    const float4* rj = (const float4*)(G4 + j * GSTR);
    float a = 0.0f;
    #pragma unroll
    for (int k = 0; k < GSTR / 4; ++k) {
      const float4 x = ri[k], y = rj[k];
      a += x.x * y.x + x.y * y.y + x.z * y.z + x.w * y.w;
    }
    G2[i * GSTR + j] = a;
    G2[j * GSTR + i] = a;
  }
  __syncthreads();

  // ---- D2. wave 0: power iteration on G8 (renorm every iter); waves 1..5 zero Y+R
  if (wave == 0) {
    float g8r[36];
    #pragma unroll
    for (int j = 0; j < 36; ++j) g8r[j] = (lane < 36) ? G2[lane * GSTR + j] : 0.0f;
    float v = (lane < 36) ? 1.0f : 0.0f;
    for (int it = 0; it < PITER8; ++it) {
      const int vi = __float_as_int(v);
      float w0 = 0.0f, w1 = 0.0f, w2 = 0.0f, w3 = 0.0f;
      #pragma unroll
      for (int j = 0; j < 36; j += 4) {
        w0 = fmaf(g8r[j],     __int_as_float(__builtin_amdgcn_readlane(vi, j)),     w0);
        w1 = fmaf(g8r[j + 1], __int_as_float(__builtin_amdgcn_readlane(vi, j + 1)), w1);
        w2 = fmaf(g8r[j + 2], __int_as_float(__builtin_amdgcn_readlane(vi, j + 2)), w2);
        w3 = fmaf(g8r[j + 3], __int_as_float(__builtin_amdgcn_readlane(vi, j + 3)), w3);
      }
      float w = (w0 + w1) + (w2 + w3);
      float s = w * w;
      #pragma unroll
      for (int off = 32; off > 0; off >>= 1) s += __shfl_xor(s, off, 64);
      v = w * rsqrtf(s);
    }
    // Rayleigh on ORIGINAL G (v is unit)
    const int vi = __float_as_int(v);
    float w0 = 0.0f, w1 = 0.0f;
    #pragma unroll
    for (int j = 0; j < 36; j += 2) {
      const float gi0 = (lane < 36) ? Gs[lane * GSTR + j]     : 0.0f;
      const float gi1 = (lane < 36) ? Gs[lane * GSTR + j + 1] : 0.0f;
      w0 = fmaf(gi0, __int_as_float(__builtin_amdgcn_readlane(vi, j)),     w0);
      w1 = fmaf(gi1, __int_as_float(__builtin_amdgcn_readlane(vi, j + 1)), w1);
    }
    float num = v * (w0 + w1);
    #pragma unroll
    for (int off = 32; off > 0; off >>= 1) num += __shfl_xor(num, off, 64);
    if (lane == 0) {
      sc[0] = 1.0f / num;        // L_inv
      sc[1] = 0.1f / num;        // thr = lam_f * L_inv
    }
  } else {
    unsigned int* z = (unsigned int*)smc;
    for (int i = tid - 64; i < (BY_R + 4096) / 4; i += 320) z[i] = 0u;  // Y+R zero
  }
  __syncthreads();
  const float L_inv = sc[0];
  const float thr = sc[1];

  float xR[2][2][4], yR[2][2][4];       // [pt-idx][stripe][r]
  #pragma unroll
  for (int k = 0; k < 2; ++k)
    #pragma unroll
    for (int s = 0; s < 2; ++s)
      #pragma unroll
      for (int r = 0; r < 4; ++r) { xR[k][s][r] = 0.0f; yR[k][s][r] = 0.0f; }

  float tk = 1.0f;

  // ---- F. FISTA loop (R8 body at N=32, 6 waves; 2 desynced blocks per CU)
  for (int it = 0; it < NITER; ++it) {
    // phase A (all 6 waves): R = Y - D y   (M=48, N=32, K=192)
    {
      floatx4 aH0 = {0.f,0.f,0.f,0.f}, aH1 = {0.f,0.f,0.f,0.f};
      floatx4 aL0 = {0.f,0.f,0.f,0.f}, aL1 = {0.f,0.f,0.f,0.f};
      const int n0 = 16 * ntA + ln;
      const char* yrow = smc + BY_Y + n0 * YROW;
      #pragma unroll
      for (int ks = 0; ks < NKA; ++ks) {
        const int kb = (32 * ks + 8 * q) * 2;
        const half8 b0 = *(const half8*)(yrow + SWZ(n0, kb));
        if (ks & 1) {
          aH1 = MFMA16(DhF[ks], b0, aH1, 0, 0, 0);
          aL1 = MFMA16(DlF[ks], b0, aL1, 0, 0, 0);
        } else {
          aH0 = MFMA16(DhF[ks], b0, aH0, 0, 0, 0);
          aL0 = MFMA16(DlF[ks], b0, aL0, 0, 0, 0);
        }
      }
      const int t0 = 16 * mtA + 4 * q;
      half4 hv;
      #pragma unroll
      for (int r = 0; r < 4; ++r)
        hv[r] = (half_t)(yA[r] - ((aH0[r] + aH1[r]) + (aL0[r] + aL1[r])));
      *(half4*)(smc + BY_R + n0 * RROW + SWZ(n0, t0 * 2)) = hv;
    }
    __syncthreads();

    const float tnew = 0.5f * (1.0f + sqrtf(1.0f + 4.0f * tk * tk));
    const float ttf = (tk - 1.0f) / tnew;
    tk = tnew;

    // phase B: w = y + L_inv D^T R ; shrink + momentum  (hi-only D^T)
    // Wave reads both stripes of R (4 b128), reused for its 2 pt tiles.
    {
      half8 rb[2][2];
      #pragma unroll
      for (int s = 0; s < 2; ++s) {
        const int cS = 16 * s + ln;
        const char* rrow = smc + BY_R + cS * RROW;
        rb[s][0] = *(const half8*)(rrow + SWZ(cS, 16 * q));        // t = 8q..8q+7
        rb[s][1] = *(const half8*)(rrow + SWZ(cS, 64 + 16 * q));   // t = 32+8q (pads 0)
      }

      #pragma unroll
      for (int k = 0; k < 2; ++k) {
        const int pt = g + 6 * k;
        const int p0 = 16 * pt + 4 * q;
        #pragma unroll
        for (int s = 0; s < 2; ++s) {
          floatx4 a = {0.f,0.f,0.f,0.f};
          a = MFMA16(DtH[k][0], rb[s][0], a, 0, 0, 0);
          a = MFMA16(DtH[k][1], rb[s][1], a, 0, 0, 0);
          const int cS = 16 * s + ln;
          half4 hv;
          #pragma unroll
          for (int r = 0; r < 4; ++r) {
            const float w = yR[k][s][r] + L_inv * a[r];
            const float cl = fminf(fmaxf(w, -thr), thr);   // v_med3 clamp
            const float xn = w - cl;                        // softshrink
            const float yn = xn + ttf * (xn - xR[k][s][r]);
            xR[k][s][r] = xn;
            yR[k][s][r] = yn;
            hv[r] = (half_t)yn;
          }
          *(half4*)(smc + BY_Y + cS * YROW + SWZ(cS, p0 * 2)) = hv;
        }
      }
    }
    __syncthreads();
  }

  // ---- G. outputs: C = x_fin (ghost atoms masked by p < PDIM; cols by c < DHALF)
  float* Cb = outC + b * PDIM * NCOL + dh * DHALF;
  #pragma unroll
  for (int k = 0; k < 2; ++k) {
    const int pt = g + 6 * k;
    #pragma unroll
    for (int s = 0; s < 2; ++s) {
      const int cS = 16 * s + ln;
      if (cS < DHALF) {
        #pragma unroll
        for (int r = 0; r < 4; ++r) {
          const int p = 16 * pt + 4 * q + r;
          if (p < PDIM) Cb[p * NCOL + cS] = xR[k][s][r];
        }
      }
    }
  }
  // reconst = D @ C : restage x into Y (fp16), rerun phase-A GEMM
  #pragma unroll
  for (int k = 0; k < 2; ++k) {
    const int pt = g + 6 * k;
    const int p0 = 16 * pt + 4 * q;
    #pragma unroll
    for (int s = 0; s < 2; ++s) {
      const int cS = 16 * s + ln;
      half4 hv;
      #pragma unroll
      for (int r = 0; r < 4; ++r) hv[r] = (half_t)xR[k][s][r];
      *(half4*)(smc + BY_Y + cS * YROW + SWZ(cS, p0 * 2)) = hv;
    }
  }
  __syncthreads();
  {
    floatx4 aH0 = {0.f,0.f,0.f,0.f}, aH1 = {0.f,0.f,0.f,0.f};
    floatx4 aL0 = {0.f,0.f,0.f,0.f}, aL1 = {0.f,0.f,0.f,0.f};
    const int n0 = 16 * ntA + ln;
    const char* yrow = smc + BY_Y + n0 * YROW;
    #pragma unroll
    for (int ks = 0; ks < NKA; ++ks) {
      const int kb = (32 * ks + 8 * q) * 2;
      const half8 b0 = *(const half8*)(yrow + SWZ(n0, kb));
      if (ks & 1) {
        aH1 = MFMA16(DhF[ks], b0, aH1, 0, 0, 0);
        aL1 = MFMA16(DlF[ks], b0, aL1, 0, 0, 0);
      } else {
        aH0 = MFMA16(DhF[ks], b0, aH0, 0, 0, 0);
        aL0 = MFMA16(DlF[ks], b0, aL0, 0, 0, 0);
      }
    }
    float* Rb = outR + b * TDIM * NCOL + dh * DHALF;
    const int c = n0;
    if (c < DHALF) {
      const int t0 = 16 * mtA + 4 * q;
      #pragma unroll
      for (int r = 0; r < 4; ++r) {
        const int t = t0 + r;
        if (t < TDIM)
          Rb[t * NCOL + c] = (aH0[r] + aH1[r]) + (aL0[r] + aL1[r]);
      }
    }
  }
}

// ---------------- launch --------------------------------------------------------------

extern "C" void kernel_launch(void* const* d_in, const int* in_sizes, int n_in,
                              void* d_out, int out_size, void* d_ws, size_t ws_size,
                              hipStream_t stream) {
  const float* x     = (const float*)d_in[0];   // (256, 36, 50)
  const float* rho   = (const float*)d_in[1];   // (80,)
  const float* theta = (const float*)d_in[2];   // (80,)

  float* out    = (float*)d_out;
  float* outC   = out;                              // 256*161*50
  float* outDic = out + 256 * PDIM * NCOL;          // 36*161
  float* outR   = outDic + TDIM * PDIM;             // 256*36*50

  hipLaunchKernelGGL(dan_kernel, dim3(512), dim3(384), LDS_TOTAL, stream,
                     x, rho, theta, outC, outDic, outR);
}

// Round 12
// 290.499 us; speedup vs baseline: 1.0711x; 1.0711x over previous
//
#include <hip/hip_runtime.h>
#include <math.h>

typedef _Float16 half_t;
typedef __attribute__((ext_vector_type(8))) _Float16 half8;
typedef __attribute__((ext_vector_type(4))) _Float16 half4;
typedef __attribute__((ext_vector_type(4))) float floatx4;

#define TDIM 36
#define PDIM 161        // 2*80+1 atoms
#define NCOL 50
#define NITER 100
#define PITER8 50       // power steps on G^8 == 400 on G (proven config)

// COLUMN-SEPARABLE FISTA: wave w owns cols [16w,16w+16) of one batch item and
// runs BOTH GEMM phases for them -> all loop state is wave-private -> ZERO
// __syncthreads in the 100-iter loop (the R8 barrier drain was ~50% of time;
// R2/R9/R10 showed 2-block desync can't be scheduled without spilling).
// Grid: 256 blocks x 256 threads (4 waves, 1/SIMD). At 1 wave/SIMD, VGPR is
// free up to 256 -> x/y f32 state in regs; D/Dt fragments re-read from LDS.
// phase A (per wave): M=48 (3 mt), N=16, K=192 (6 ks), D hi/lo -> 36 MFMA
// phase B (per wave): M=176 (11 pt), N=16, K=64 (2 ks), D^T hi-only -> 22 MFMA
#define NKA 6
#define GSTR 44
#define SPS 196         // Df (fp32) row stride (dwords)

// row strides in BYTES
#define YROW 384        // y^T  [64 cols][192 atoms] half
#define RROW 128        // R^T  [64 cols][64 t] half
#define DROW 384        // Dah/Dal [48 t][192 atoms] half (phase-A A-operand)
#define TROW 128        // Dth  [176 atoms][64 t] half (phase-B A-operand)

// XOR swizzle: spread same-column reads across 8 rows -> 8 distinct 16B slots
#define SWZ(row, byteoff) ((byteoff) ^ (((row) & 7) << 4))

// ---- byte-offset LDS map: 111,184 B (1 block/CU) ----
#define BY_Y    0                      // 24,576
#define BY_R    24576                  //  8,192
#define BY_LRTH 28672                  //  1,288 (in R region, past Df end 28,224)
#define BY_SC   32768                  //     16
#define BY_DAH  32784                  // 18,432
#define BY_DAL  51216                  // 18,432
#define BY_DTH  69648                  // 22,528
#define BY_GS   92176                  //  6,336
#define BY_G2   98512                  //  6,336 (holds G^2, later G^8)
#define BY_G4   104848                 //  6,336
#define LDS_TOTAL 111184
// setup alias: Df fp32 [36][196] = 28,224 B over Y + head of R (zeroed pre-loop)

#define MFMA16 __builtin_amdgcn_mfma_f32_16x16x32_f16

__global__ __launch_bounds__(256, 1)
void dan_kernel(const float* __restrict__ xin, const float* __restrict__ rho,
                const float* __restrict__ theta, float* __restrict__ outC,
                float* __restrict__ outDic, float* __restrict__ outR)
{
  extern __shared__ char smc[];
  float*  sc   = (float*)(smc + BY_SC);
  float*  Gs   = (float*)(smc + BY_GS);
  float*  G2   = (float*)(smc + BY_G2);
  float*  G4   = (float*)(smc + BY_G4);
  float*  Df   = (float*)(smc + BY_Y);    // setup alias (28,224 B)
  float*  lrth = (float*)(smc + BY_LRTH); // [161] lr, [161] th (setup only)

  const int tid = threadIdx.x;
  const int b = blockIdx.x;
  const int wave = tid >> 6, lane = tid & 63;
  const int q = lane >> 4, ln = lane & 15;
  const int col = 16 * wave + ln;       // this wave's column slot (0..63)

  // ---- A. zero all LDS (pads must be 0)
  {
    unsigned int* z = (unsigned int*)smc;
    for (int i = tid; i < LDS_TOTAL / 4; i += 256) z[i] = 0u;
  }
  __syncthreads();

  // ---- B0. per-atom lr/th
  if (tid >= 1 && tid < PDIM) {
    const bool is_sin = tid > 80;
    const int n = is_sin ? (tid - 81) : (tid - 1);
    lrth[tid]       = logf(0.001f + 1.149f / (1.0f + expf(-rho[n])));
    lrth[161 + tid] = 3.14159265358979f / (1.0f + expf(-theta[n]));
  }
  __syncthreads();

  // ---- B1. raw dictionary
  for (int i = tid; i < TDIM * PDIM; i += 256) {
    const int t = i / PDIM, p = i - t * PDIM;
    float val;
    if (p == 0) {
      val = 1.0f;
    } else {
      const float ft = (float)t;
      const float e = expf(ft * lrth[p]);
      const float ang = ft * lrth[161 + p];
      val = e * (p > 80 ? sinf(ang) : cosf(ang));
    }
    Df[t * SPS + p] = val;
  }
  __syncthreads();

  // ---- B2. column-normalize (atoms 1..160)
  if (tid >= 1 && tid < PDIM) {
    float s2 = 0.0f;
    for (int t = 0; t < TDIM; ++t) {
      const float v = Df[t * SPS + tid];
      s2 += v * v;
    }
    const float inv = 1.0f / sqrtf(s2);
    for (int t = 0; t < TDIM; ++t) Df[t * SPS + tid] *= inv;
  }
  __syncthreads();

  // ---- C. Gram -> Gs ; stage Dah/Dal (A-layout) + Dth (B-layout) ; dic out
  for (int job = tid; job < 666; job += 256) {   // 666 = 36*37/2
    int i = 0, rem = job;
    while (rem >= TDIM - i) { rem -= TDIM - i; ++i; }
    const int j = i + rem;
    const float4* ri = (const float4*)(Df + i * SPS);
    const float4* rj = (const float4*)(Df + j * SPS);
    float a = 0.0f;
    #pragma unroll 7
    for (int k = 0; k < SPS / 4; ++k) {
      const float4 x = ri[k], y = rj[k];
      a += x.x * y.x + x.y * y.y + x.z * y.z + x.w * y.w;
    }
    Gs[i * GSTR + j] = a;
    Gs[j * GSTR + i] = a;
  }
  for (int i = tid; i < TDIM * PDIM; i += 256) {
    const int t = i / PDIM, p = i - t * PDIM;
    const float v = Df[t * SPS + p];
    const half_t h = (half_t)v;
    const half_t l = (half_t)(v - (float)h);
    *(half_t*)(smc + BY_DAH + t * DROW + SWZ(t, p * 2)) = h;
    *(half_t*)(smc + BY_DAL + t * DROW + SWZ(t, p * 2)) = l;
    *(half_t*)(smc + BY_DTH + p * TROW + SWZ(p, t * 2)) = h;
    if (b == 0) outDic[i] = v;
  }
  // static Y (fp32) at phase-A C positions: yA[mt][r] for this wave's cols
  float yA[3][4];
  {
    const float* xb = xin + b * TDIM * NCOL;
    #pragma unroll
    for (int mt = 0; mt < 3; ++mt) {
      #pragma unroll
      for (int r = 0; r < 4; ++r) {
        const int t = 16 * mt + 4 * q + r;
        yA[mt][r] = (t < TDIM && col < NCOL) ? xb[t * NCOL + col] : 0.0f;
      }
    }
  }
  __syncthreads();

  // ---- C2. G2 = G*G
  for (int job = tid; job < 666; job += 256) {
    int i = 0, rem = job;
    while (rem >= TDIM - i) { rem -= TDIM - i; ++i; }
    const int j = i + rem;
    const float4* ri = (const float4*)(Gs + i * GSTR);
    const float4* rj = (const float4*)(Gs + j * GSTR);
    float a = 0.0f;
    #pragma unroll
    for (int k = 0; k < GSTR / 4; ++k) {
      const float4 x = ri[k], y = rj[k];
      a += x.x * y.x + x.y * y.y + x.z * y.z + x.w * y.w;
    }
    G2[i * GSTR + j] = a;
    G2[j * GSTR + i] = a;
  }
  __syncthreads();
  // ---- C3. G4 = G2*G2
  for (int job = tid; job < 666; job += 256) {
    int i = 0, rem = job;
    while (rem >= TDIM - i) { rem -= TDIM - i; ++i; }
    const int j = i + rem;
    const float4* ri = (const float4*)(G2 + i * GSTR);
    const float4* rj = (const float4*)(G2 + j * GSTR);
    float a = 0.0f;
    #pragma unroll
    for (int k = 0; k < GSTR / 4; ++k) {
      const float4 x = ri[k], y = rj[k];
      a += x.x * y.x + x.y * y.y + x.z * y.z + x.w * y.w;
    }
    G4[i * GSTR + j] = a;
    G4[j * GSTR + i] = a;
  }
  __syncthreads();
  // ---- C4. G8 = G4*G4 -> overwrite G2
  for (int job = tid; job < 666; job += 256) {
    int i = 0, rem = job;
    while (rem >= TDIM - i) { rem -= TDIM - i; ++i; }
    const int j = i + rem;
    const float4* ri = (const float4*)(G4 + i * GSTR);
    const float4* rj = (const float4*)(G4 + j * GSTR);
    float a = 0.0f;
    #pragma unroll
    for (int k = 0; k < GSTR / 4; ++k) {
      const float4 x = ri[k], y = rj[k];
      a += x.x * y.x + x.y * y.y + x.z * y.z + x.w * y.w;
    }
    G2[i * GSTR + j] = a;
    G2[j * GSTR + i] = a;
  }
  __syncthreads();

  // ---- D2. wave 0: power iteration on G8 ; waves 1..3: zero Y+R (kills Df alias)
  if (wave == 0) {
    float g8r[36];
    #pragma unroll
    for (int j = 0; j < 36; ++j) g8r[j] = (lane < 36) ? G2[lane * GSTR + j] : 0.0f;
    float v = (lane < 36) ? 1.0f : 0.0f;
    for (int it = 0; it < PITER8; ++it) {
      const int vi = __float_as_int(v);
      float w0 = 0.0f, w1 = 0.0f, w2 = 0.0f, w3 = 0.0f;
      #pragma unroll
      for (int j = 0; j < 36; j += 4) {
        w0 = fmaf(g8r[j],     __int_as_float(__builtin_amdgcn_readlane(vi, j)),     w0);
        w1 = fmaf(g8r[j + 1], __int_as_float(__builtin_amdgcn_readlane(vi, j + 1)), w1);
        w2 = fmaf(g8r[j + 2], __int_as_float(__builtin_amdgcn_readlane(vi, j + 2)), w2);
        w3 = fmaf(g8r[j + 3], __int_as_float(__builtin_amdgcn_readlane(vi, j + 3)), w3);
      }
      float w = (w0 + w1) + (w2 + w3);
      float s = w * w;
      #pragma unroll
      for (int off = 32; off > 0; off >>= 1) s += __shfl_xor(s, off, 64);
      v = w * rsqrtf(s);
    }
    // Rayleigh on ORIGINAL G (v is unit)
    const int vi = __float_as_int(v);
    float w0 = 0.0f, w1 = 0.0f;
    #pragma unroll
    for (int j = 0; j < 36; j += 2) {
      const float gi0 = (lane < 36) ? Gs[lane * GSTR + j]     : 0.0f;
      const float gi1 = (lane < 36) ? Gs[lane * GSTR + j + 1] : 0.0f;
      w0 = fmaf(gi0, __int_as_float(__builtin_amdgcn_readlane(vi, j)),     w0);
      w1 = fmaf(gi1, __int_as_float(__builtin_amdgcn_readlane(vi, j + 1)), w1);
    }
    float num = v * (w0 + w1);
    #pragma unroll
    for (int off = 32; off > 0; off >>= 1) num += __shfl_xor(num, off, 64);
    if (lane == 0) {
      sc[0] = 1.0f / num;        // L_inv
      sc[1] = 0.1f / num;        // thr = lam_f * L_inv
    }
  } else {
    unsigned int* z = (unsigned int*)smc;
    for (int i = tid - 64; i < (BY_R + 8192) / 4; i += 192) z[i] = 0u;  // Y+R zero
  }
  __syncthreads();
  const float L_inv = sc[0];
  const float thr = sc[1];

  // wave-private FISTA state (f32, registers): 11 pt tiles x 4 rows
  float xS[11][4], yS[11][4];
  #pragma unroll
  for (int pt = 0; pt < 11; ++pt)
    #pragma unroll
    for (int r = 0; r < 4; ++r) { xS[pt][r] = 0.0f; yS[pt][r] = 0.0f; }

  float tk = 1.0f;

  // ---- F. FISTA loop: NO BARRIERS (all data wave-private; LDS deps in-order)
  for (int it = 0; it < NITER; ++it) {
    // y fragments for this wave's cols (shared across the 3 mt tiles)
    half8 yb[NKA];
    {
      const char* yrow = smc + BY_Y + col * YROW;
      #pragma unroll
      for (int ks = 0; ks < NKA; ++ks)
        yb[ks] = *(const half8*)(yrow + SWZ(col, (32 * ks + 8 * q) * 2));
    }
    // phase A: R[t, cols] = Y - D y   (3 mt tiles, D hi/lo from LDS)
    #pragma unroll
    for (int mt = 0; mt < 3; ++mt) {
      const int row = 16 * mt + ln;
      const char* dah = smc + BY_DAH + row * DROW;
      const char* dal = smc + BY_DAL + row * DROW;
      floatx4 aH = {0.f,0.f,0.f,0.f}, aL = {0.f,0.f,0.f,0.f};
      #pragma unroll
      for (int ks = 0; ks < NKA; ++ks) {
        const int kb = (32 * ks + 8 * q) * 2;
        const half8 ah = *(const half8*)(dah + SWZ(row, kb));
        const half8 al = *(const half8*)(dal + SWZ(row, kb));
        aH = MFMA16(ah, yb[ks], aH, 0, 0, 0);
        aL = MFMA16(al, yb[ks], aL, 0, 0, 0);
      }
      const int t0 = 16 * mt + 4 * q;
      half4 hv;
      #pragma unroll
      for (int r = 0; r < 4; ++r)
        hv[r] = (half_t)(yA[mt][r] - (aH[r] + aL[r]));
      *(half4*)(smc + BY_R + col * RROW + SWZ(col, t0 * 2)) = hv;
    }

    const float tnew = 0.5f * (1.0f + sqrtf(1.0f + 4.0f * tk * tk));
    const float ttf = (tk - 1.0f) / tnew;
    tk = tnew;

    // phase B: w = y + L_inv D^T R ; shrink + momentum (11 pt tiles, Dt hi-only)
    {
      const char* rrow = smc + BY_R + col * RROW;
      const half8 rb0 = *(const half8*)(rrow + SWZ(col, (8 * q) * 2));
      const half8 rb1 = *(const half8*)(rrow + SWZ(col, (32 + 8 * q) * 2)); // pads 0
      #pragma unroll
      for (int pt = 0; pt < 11; ++pt) {
        const int rowT = 16 * pt + ln;
        const char* th = smc + BY_DTH + rowT * TROW;
        floatx4 a = {0.f,0.f,0.f,0.f};
        a = MFMA16(*(const half8*)(th + SWZ(rowT, (8 * q) * 2)),        rb0, a, 0, 0, 0);
        a = MFMA16(*(const half8*)(th + SWZ(rowT, (32 + 8 * q) * 2)),   rb1, a, 0, 0, 0);
        const int p0 = 16 * pt + 4 * q;
        half4 hv;
        #pragma unroll
        for (int r = 0; r < 4; ++r) {
          const float w = yS[pt][r] + L_inv * a[r];
          const float cl = fminf(fmaxf(w, -thr), thr);   // v_med3 clamp
          const float xn = w - cl;                        // softshrink
          const float yn = xn + ttf * (xn - xS[pt][r]);
          xS[pt][r] = xn;
          yS[pt][r] = yn;
          hv[r] = (half_t)yn;
        }
        *(half4*)(smc + BY_Y + col * YROW + SWZ(col, p0 * 2)) = hv;
      }
    }
  }

  // ---- G. outputs: C = x_fin (wave-private; no barrier needed)
  float* Cb = outC + b * PDIM * NCOL;
  if (col < NCOL) {
    #pragma unroll
    for (int pt = 0; pt < 11; ++pt) {
      #pragma unroll
      for (int r = 0; r < 4; ++r) {
        const int p = 16 * pt + 4 * q + r;
        if (p < PDIM) Cb[p * NCOL + col] = xS[pt][r];
      }
    }
  }
  // reconst = D @ C : restage x into Y16 (own cols), rerun phase A
  #pragma unroll
  for (int pt = 0; pt < 11; ++pt) {
    const int p0 = 16 * pt + 4 * q;
    half4 hv;
    #pragma unroll
    for (int r = 0; r < 4; ++r) hv[r] = (half_t)xS[pt][r];
    *(half4*)(smc + BY_Y + col * YROW + SWZ(col, p0 * 2)) = hv;
  }
  {
    half8 xb8[NKA];
    const char* yrow = smc + BY_Y + col * YROW;
    #pragma unroll
    for (int ks = 0; ks < NKA; ++ks)
      xb8[ks] = *(const half8*)(yrow + SWZ(col, (32 * ks + 8 * q) * 2));
    float* Rb = outR + b * TDIM * NCOL;
    #pragma unroll
    for (int mt = 0; mt < 3; ++mt) {
      const int row = 16 * mt + ln;
      const char* dah = smc + BY_DAH + row * DROW;
      const char* dal = smc + BY_DAL + row * DROW;
      floatx4 aH = {0.f,0.f,0.f,0.f}, aL = {0.f,0.f,0.f,0.f};
      #pragma unroll
      for (int ks = 0; ks < NKA; ++ks) {
        const int kb = (32 * ks + 8 * q) * 2;
        const half8 ah = *(const half8*)(dah + SWZ(row, kb));
        const half8 al = *(const half8*)(dal + SWZ(row, kb));
        aH = MFMA16(ah, xb8[ks], aH, 0, 0, 0);
        aL = MFMA16(al, xb8[ks], aL, 0, 0, 0);
      }
      if (col < NCOL) {
        const int t0 = 16 * mt + 4 * q;
        #pragma unroll
        for (int r = 0; r < 4; ++r) {
          const int t = t0 + r;
          if (t < TDIM) Rb[t * NCOL + col] = aH[r] + aL[r];
        }
      }
    }
  }
}

// ---------------- launch --------------------------------------------------------------

extern "C" void kernel_launch(void* const* d_in, const int* in_sizes, int n_in,
                              void* d_out, int out_size, void* d_ws, size_t ws_size,
                              hipStream_t stream) {
  const float* x     = (const float*)d_in[0];   // (256, 36, 50)
  const float* rho   = (const float*)d_in[1];   // (80,)
  const float* theta = (const float*)d_in[2];   // (80,)

  float* out    = (float*)d_out;
  float* outC   = out;                              // 256*161*50
  float* outDic = out + 256 * PDIM * NCOL;          // 36*161
  float* outR   = outDic + TDIM * PDIM;             // 256*36*50

  hipLaunchKernelGGL(dan_kernel, dim3(256), dim3(256), LDS_TOTAL, stream,
                     x, rho, theta, outC, outDic, outR);
}

// Round 13
// 211.245 us; speedup vs baseline: 1.4729x; 1.3752x over previous
//
#include <hip/hip_runtime.h>
#include <math.h>

typedef _Float16 half_t;
typedef __attribute__((ext_vector_type(8))) _Float16 half8;
typedef __attribute__((ext_vector_type(4))) _Float16 half4;
typedef __attribute__((ext_vector_type(4))) float floatx4;

#define TDIM 36
#define PDIM 161        // 2*80+1 atoms
#define NCOL 50
#define NITER 100
#define PITER8 50       // power steps on G^8 == 400 on G (proven config)

// R8 structure (175.6 us proven: 768 thr, 12 waves, 3/SIMD) + VALU diet:
//  - ttf momentum table precomputed in setup (data-independent; 1 ds_read/iter
//    replaces per-wave sqrt+div chain)
//  - all 15 loop-invariant swizzled LDS addresses hoisted to registers
// phase A: M=48,N=64,K=192 (6 ks), 12 waves = 3 mt x 4 nt, D hi/lo (12 MFMA)
// phase B: M=192 (12 pt incl ghost pt=11), N=64, K=64; wave (g=w>>1,h=w&1)
//          owns pt in {g,g+6}, stripes {2h,2h+1}; D^T hi ONLY -> 8 MFMA/wave.
// R12 LESSON: barrier-free @1 wave/SIMD = 262 us (latency-exposed); the 12-wave
// lock-step with 2 barriers is the better regime. R9/R10: multi-block desync
// unschedulable without spill. This round attacks the 54% VALUBusy instead.
#define NKA 6
#define GSTR 44
#define SPS 196         // Df (fp32) row stride (dwords)

// row strides in BYTES
#define YROW 384        // y^T [64][192] half
#define RROW 128        // R^T [64][64] half

// XOR swizzle: spread same-column reads across 8 rows -> 8 distinct 16B slots
#define SWZ(row, byteoff) ((byteoff) ^ (((row) & 7) << 4))

// ---- byte-offset LDS map: 52,192 B ----
#define BY_Y    0                      // 24,576
#define BY_R    24576                  //  8,192
#define BY_LRTH 28672                  //  1,288 (inside R region, past Df end 28,224)
#define BY_SC   32768                  //     16
#define BY_TTF  32784                  //    400 (ttf[100] momentum table)
#define BY_GS   33184                  //  6,336
#define BY_G2   39520                  //  6,336  (holds G^2, later overwritten by G^8)
#define BY_G4   45856                  //  6,336
#define LDS_TOTAL 52192
// setup alias: Df fp32 [36][196] = 28,224 B over Y + head of R (re-zeroed pre-loop)

#define MFMA16 __builtin_amdgcn_mfma_f32_16x16x32_f16

__global__ __launch_bounds__(768, 3)
void dan_kernel(const float* __restrict__ xin, const float* __restrict__ rho,
                const float* __restrict__ theta, float* __restrict__ outC,
                float* __restrict__ outDic, float* __restrict__ outR)
{
  extern __shared__ char smc[];
  float*  sc   = (float*)(smc + BY_SC);
  float*  ttfT = (float*)(smc + BY_TTF);
  float*  Gs   = (float*)(smc + BY_GS);
  float*  G2   = (float*)(smc + BY_G2);
  float*  G4   = (float*)(smc + BY_G4);
  float*  Df   = (float*)(smc + BY_Y);    // setup alias
  float*  lrth = (float*)(smc + BY_LRTH); // [161] lr, [161] th (setup only)

  const int tid = threadIdx.x;
  const int b = blockIdx.x;
  const int wave = tid >> 6, lane = tid & 63;
  const int q = lane >> 4, ln = lane & 15;

  // ---- A. zero all LDS (pads must be 0)
  {
    unsigned int* z = (unsigned int*)smc;
    for (int i = tid; i < LDS_TOTAL / 4; i += 768) z[i] = 0u;
  }
  __syncthreads();

  // ---- B0. per-atom lr/th (161 threads, 2 transcendentals each)
  if (tid >= 1 && tid < PDIM) {
    const bool is_sin = tid > 80;
    const int n = is_sin ? (tid - 81) : (tid - 1);
    lrth[tid]       = logf(0.001f + 1.149f / (1.0f + expf(-rho[n])));
    lrth[161 + tid] = 3.14159265358979f / (1.0f + expf(-theta[n]));
  }
  __syncthreads();

  // ---- B1. raw dictionary, parallel over all (t,p) jobs
  for (int i = tid; i < TDIM * PDIM; i += 768) {
    const int t = i / PDIM, p = i - t * PDIM;
    float val;
    if (p == 0) {
      val = 1.0f;
    } else {
      const float ft = (float)t;
      const float e = expf(ft * lrth[p]);
      const float ang = ft * lrth[161 + p];
      val = e * (p > 80 ? sinf(ang) : cosf(ang));
    }
    Df[t * SPS + p] = val;
  }
  __syncthreads();

  // ---- B2. column-normalize (atoms 1..160)
  if (tid >= 1 && tid < PDIM) {
    float s2 = 0.0f;
    for (int t = 0; t < TDIM; ++t) {
      const float v = Df[t * SPS + tid];
      s2 += v * v;
    }
    const float inv = 1.0f / sqrtf(s2);
    for (int t = 0; t < TDIM; ++t) Df[t * SPS + tid] *= inv;
  }
  __syncthreads();

  // ---- C. Gram -> Gs ; dic out ; load ALL MFMA fragments to registers
  if (tid < 666) {                      // 666 = 36*37/2
    int i = 0, rem = tid;
    while (rem >= TDIM - i) { rem -= TDIM - i; ++i; }
    const int j = i + rem;
    const float4* ri = (const float4*)(Df + i * SPS);
    const float4* rj = (const float4*)(Df + j * SPS);
    float a = 0.0f;
    #pragma unroll 7
    for (int k = 0; k < SPS / 4; ++k) {
      const float4 x = ri[k], y = rj[k];
      a += x.x * y.x + x.y * y.y + x.z * y.z + x.w * y.w;
    }
    Gs[i * GSTR + j] = a;
    Gs[j * GSTR + i] = a;
  }
  if (b == 0) {
    for (int i = tid; i < TDIM * PDIM; i += 768) {
      const int t = i / PDIM, p = i - t * PDIM;
      outDic[i] = Df[t * SPS + p];
    }
  }

  // ownership maps
  const int mtA = wave >> 2;            // phase A: 3 mt x 4 nt, one tile per wave
  const int ntA = wave & 3;
  const int g = wave >> 1;              // phase B: pt in {g, g+6} (pt=11 = ghost)
  const int h = wave & 1;               //          stripes {2h, 2h+1}

  // phase-A A-fragments (D hi/lo); rows >= 36 are zero (Df region zero there)
  half8 DhF[NKA], DlF[NKA];
  {
    const int row = 16 * mtA + ln;
    #pragma unroll
    for (int ks = 0; ks < NKA; ++ks) {
      half8 hh = {0,0,0,0,0,0,0,0}, ll = {0,0,0,0,0,0,0,0};
      if (row < TDIM) {
        const float4 f0 = *(const float4*)(Df + row * SPS + 32 * ks + 8 * q);
        const float4 f1 = *(const float4*)(Df + row * SPS + 32 * ks + 8 * q + 4);
        const float fa[8] = {f0.x, f0.y, f0.z, f0.w, f1.x, f1.y, f1.z, f1.w};
        #pragma unroll
        for (int e = 0; e < 8; ++e) {
          const half_t h2 = (half_t)fa[e];
          hh[e] = h2;
          ll[e] = (half_t)(fa[e] - (float)h2);
        }
      }
      DhF[ks] = hh;
      DlF[ks] = ll;
    }
  }
  // phase-B A-fragments (D^T hi ONLY), transposed read from Df; atoms>=161 zero
  half8 DtH[2][2];                      // [k][ks]
  #pragma unroll
  for (int k = 0; k < 2; ++k) {
    const int atom = 16 * (g + 6 * k) + ln;         // 0..191 (>=161 -> zero cols)
    #pragma unroll
    for (int ks = 0; ks < 2; ++ks) {
      half8 hh;
      #pragma unroll
      for (int e = 0; e < 8; ++e) {
        const int t = 32 * ks + 8 * q + e;
        const float v = (t < TDIM) ? Df[t * SPS + atom] : 0.0f;
        hh[e] = (half_t)v;
      }
      DtH[k][ks] = hh;
    }
  }
  // static Y (fp32) at phase-A C positions
  float yA[4];
  {
    const float* xb = xin + b * TDIM * NCOL;
    const int c = 16 * ntA + ln;
    #pragma unroll
    for (int r = 0; r < 4; ++r) {
      const int t = 16 * mtA + 4 * q + r;
      yA[r] = (t < TDIM && c < NCOL) ? xb[t * NCOL + c] : 0.0f;
    }
  }
  __syncthreads();

  // ---- C2. G2 = G*G  (pads of all Gram buffers are zero)
  if (tid < 666) {
    int i = 0, rem = tid;
    while (rem >= TDIM - i) { rem -= TDIM - i; ++i; }
    const int j = i + rem;
    const float4* ri = (const float4*)(Gs + i * GSTR);
    const float4* rj = (const float4*)(Gs + j * GSTR);
    float a = 0.0f;
    #pragma unroll
    for (int k = 0; k < GSTR / 4; ++k) {
      const float4 x = ri[k], y = rj[k];
      a += x.x * y.x + x.y * y.y + x.z * y.z + x.w * y.w;
    }
    G2[i * GSTR + j] = a;
    G2[j * GSTR + i] = a;
  }
  __syncthreads();
  // ---- C3. G4 = G2*G2
  if (tid < 666) {
    int i = 0, rem = tid;
    while (rem >= TDIM - i) { rem -= TDIM - i; ++i; }
    const int j = i + rem;
    const float4* ri = (const float4*)(G2 + i * GSTR);
    const float4* rj = (const float4*)(G2 + j * GSTR);
    float a = 0.0f;
    #pragma unroll
    for (int k = 0; k < GSTR / 4; ++k) {
      const float4 x = ri[k], y = rj[k];
      a += x.x * y.x + x.y * y.y + x.z * y.z + x.w * y.w;
    }
    G4[i * GSTR + j] = a;
    G4[j * GSTR + i] = a;
  }
  __syncthreads();
  // ---- C4. G8 = G4*G4 -> overwrite G2 buffer
  if (tid < 666) {
    int i = 0, rem = tid;
    while (rem >= TDIM - i) { rem -= TDIM - i; ++i; }
    const int j = i + rem;
    const float4* ri = (const float4*)(G4 + i * GSTR);
    const float4* rj = (const float4*)(G4 + j * GSTR);
    float a = 0.0f;
    #pragma unroll
    for (int k = 0; k < GSTR / 4; ++k) {
      const float4 x = ri[k], y = rj[k];
      a += x.x * y.x + x.y * y.y + x.z * y.z + x.w * y.w;
    }
    G2[i * GSTR + j] = a;
    G2[j * GSTR + i] = a;
  }
  __syncthreads();

  // ---- D2. wave 0: power iteration on G8 ; others: zero Y+R ; tid64: ttf table
  if (wave == 0) {
    float g8r[36];
    #pragma unroll
    for (int j = 0; j < 36; ++j) g8r[j] = (lane < 36) ? G2[lane * GSTR + j] : 0.0f;
    float v = (lane < 36) ? 1.0f : 0.0f;
    for (int it = 0; it < PITER8; ++it) {
      const int vi = __float_as_int(v);
      float w0 = 0.0f, w1 = 0.0f, w2 = 0.0f, w3 = 0.0f;
      #pragma unroll
      for (int j = 0; j < 36; j += 4) {
        w0 = fmaf(g8r[j],     __int_as_float(__builtin_amdgcn_readlane(vi, j)),     w0);
        w1 = fmaf(g8r[j + 1], __int_as_float(__builtin_amdgcn_readlane(vi, j + 1)), w1);
        w2 = fmaf(g8r[j + 2], __int_as_float(__builtin_amdgcn_readlane(vi, j + 2)), w2);
        w3 = fmaf(g8r[j + 3], __int_as_float(__builtin_amdgcn_readlane(vi, j + 3)), w3);
      }
      float w = (w0 + w1) + (w2 + w3);
      float s = w * w;
      #pragma unroll
      for (int off = 32; off > 0; off >>= 1) s += __shfl_xor(s, off, 64);
      v = w * rsqrtf(s);
    }
    // Rayleigh on ORIGINAL G (v is unit)
    const int vi = __float_as_int(v);
    float w0 = 0.0f, w1 = 0.0f;
    #pragma unroll
    for (int j = 0; j < 36; j += 2) {
      const float gi0 = (lane < 36) ? Gs[lane * GSTR + j]     : 0.0f;
      const float gi1 = (lane < 36) ? Gs[lane * GSTR + j + 1] : 0.0f;
      w0 = fmaf(gi0, __int_as_float(__builtin_amdgcn_readlane(vi, j)),     w0);
      w1 = fmaf(gi1, __int_as_float(__builtin_amdgcn_readlane(vi, j + 1)), w1);
    }
    float num = v * (w0 + w1);
    #pragma unroll
    for (int off = 32; off > 0; off >>= 1) num += __shfl_xor(num, off, 64);
    if (lane == 0) {
      sc[0] = 1.0f / num;        // L_inv
      sc[1] = 0.1f / num;        // thr = lam_f * L_inv
    }
  } else {
    unsigned int* z = (unsigned int*)smc;
    for (int i = tid - 64; i < 32768 / 4; i += 704) z[i] = 0u;   // kill Df alias; y0=0
    if (tid == 64) {
      // data-independent momentum table; EXACT same f32 ops as the old in-loop code
      float t = 1.0f;
      for (int it = 0; it < NITER; ++it) {
        const float tn = 0.5f * (1.0f + sqrtf(1.0f + 4.0f * t * t));
        ttfT[it] = (t - 1.0f) / tn;
        t = tn;
      }
    }
  }
  __syncthreads();
  const float L_inv = sc[0];
  const float thr = sc[1];

  // ---- hoisted loop-invariant LDS addresses (15 pointers, unroll-const indexed)
  const int n0A = 16 * ntA + ln;
  const int t0A = 16 * mtA + 4 * q;
  const char* yrdA[NKA];
  #pragma unroll
  for (int ks = 0; ks < NKA; ++ks)
    yrdA[ks] = smc + BY_Y + n0A * YROW + SWZ(n0A, (32 * ks + 8 * q) * 2);
  char* rwrA = smc + BY_R + n0A * RROW + SWZ(n0A, t0A * 2);

  const char* rrdB[2][2];               // [s][ks]
  char* ywrB[2][2];                     // [k][s]
  #pragma unroll
  for (int s = 0; s < 2; ++s) {
    const int cS = 16 * (2 * h + s) + ln;
    rrdB[s][0] = smc + BY_R + cS * RROW + SWZ(cS, 16 * q);
    rrdB[s][1] = smc + BY_R + cS * RROW + SWZ(cS, 64 + 16 * q);
    #pragma unroll
    for (int k = 0; k < 2; ++k) {
      const int p0 = 16 * (g + 6 * k) + 4 * q;
      ywrB[k][s] = smc + BY_Y + cS * YROW + SWZ(cS, p0 * 2);
    }
  }

  float xR[2][2][4], yR[2][2][4];       // [pt-idx][stripe][r]
  #pragma unroll
  for (int k = 0; k < 2; ++k)
    #pragma unroll
    for (int s = 0; s < 2; ++s)
      #pragma unroll
      for (int r = 0; r < 4; ++r) { xR[k][s][r] = 0.0f; yR[k][s][r] = 0.0f; }

  // ---- F. FISTA loop (R8 body; ttf from table; addresses precomputed)
  for (int it = 0; it < NITER; ++it) {
    // phase A (all 12 waves): R = Y - D y   (M=48, N=64, K=192)
    {
      floatx4 aH0 = {0.f,0.f,0.f,0.f}, aH1 = {0.f,0.f,0.f,0.f};
      floatx4 aL0 = {0.f,0.f,0.f,0.f}, aL1 = {0.f,0.f,0.f,0.f};
      #pragma unroll
      for (int ks = 0; ks < NKA; ++ks) {
        const half8 b0 = *(const half8*)(yrdA[ks]);
        if (ks & 1) {
          aH1 = MFMA16(DhF[ks], b0, aH1, 0, 0, 0);
          aL1 = MFMA16(DlF[ks], b0, aL1, 0, 0, 0);
        } else {
          aH0 = MFMA16(DhF[ks], b0, aH0, 0, 0, 0);
          aL0 = MFMA16(DlF[ks], b0, aL0, 0, 0, 0);
        }
      }
      half4 hv;
      #pragma unroll
      for (int r = 0; r < 4; ++r)
        hv[r] = (half_t)(yA[r] - ((aH0[r] + aH1[r]) + (aL0[r] + aL1[r])));
      *(half4*)rwrA = hv;
    }
    __syncthreads();

    const float ttf = ttfT[it];

    // phase B: w = y + L_inv D^T R ; shrink + momentum  (hi-only D^T)
    {
      half8 rb[2][2];
      #pragma unroll
      for (int s = 0; s < 2; ++s) {
        rb[s][0] = *(const half8*)(rrdB[s][0]);
        rb[s][1] = *(const half8*)(rrdB[s][1]);
      }

      #pragma unroll
      for (int k = 0; k < 2; ++k) {
        #pragma unroll
        for (int s = 0; s < 2; ++s) {
          floatx4 a = {0.f,0.f,0.f,0.f};
          a = MFMA16(DtH[k][0], rb[s][0], a, 0, 0, 0);
          a = MFMA16(DtH[k][1], rb[s][1], a, 0, 0, 0);
          half4 hv;
          #pragma unroll
          for (int r = 0; r < 4; ++r) {
            const float w = yR[k][s][r] + L_inv * a[r];
            const float cl = fminf(fmaxf(w, -thr), thr);   // v_med3 clamp
            const float xn = w - cl;                        // softshrink
            const float yn = xn + ttf * (xn - xR[k][s][r]);
            xR[k][s][r] = xn;
            yR[k][s][r] = yn;
            hv[r] = (half_t)yn;
          }
          *(half4*)(ywrB[k][s]) = hv;
        }
      }
    }
    __syncthreads();
  }

  // ---- G. outputs: C = x_fin (ghost pt=11 masked by p<PDIM)
  float* Cb = outC + b * PDIM * NCOL;
  #pragma unroll
  for (int k = 0; k < 2; ++k) {
    const int pt = g + 6 * k;
    #pragma unroll
    for (int s = 0; s < 2; ++s) {
      const int cS = 16 * (2 * h + s) + ln;
      if (cS < NCOL) {
        #pragma unroll
        for (int r = 0; r < 4; ++r) {
          const int p = 16 * pt + 4 * q + r;
          if (p < PDIM) Cb[p * NCOL + cS] = xR[k][s][r];
        }
      }
    }
  }
  // reconst = D @ C : restage x into Y (fp16), rerun phase-A GEMM
  #pragma unroll
  for (int k = 0; k < 2; ++k) {
    #pragma unroll
    for (int s = 0; s < 2; ++s) {
      half4 hv;
      #pragma unroll
      for (int r = 0; r < 4; ++r) hv[r] = (half_t)xR[k][s][r];
      *(half4*)(ywrB[k][s]) = hv;
    }
  }
  __syncthreads();
  {
    floatx4 aH0 = {0.f,0.f,0.f,0.f}, aH1 = {0.f,0.f,0.f,0.f};
    floatx4 aL0 = {0.f,0.f,0.f,0.f}, aL1 = {0.f,0.f,0.f,0.f};
    #pragma unroll
    for (int ks = 0; ks < NKA; ++ks) {
      const half8 b0 = *(const half8*)(yrdA[ks]);
      if (ks & 1) {
        aH1 = MFMA16(DhF[ks], b0, aH1, 0, 0, 0);
        aL1 = MFMA16(DlF[ks], b0, aL1, 0, 0, 0);
      } else {
        aH0 = MFMA16(DhF[ks], b0, aH0, 0, 0, 0);
        aL0 = MFMA16(DlF[ks], b0, aL0, 0, 0, 0);
      }
    }
    float* Rb = outR + b * TDIM * NCOL;
    const int c = n0A;
    if (c < NCOL) {
      #pragma unroll
      for (int r = 0; r < 4; ++r) {
        const int t = t0A + r;
        if (t < TDIM)
          Rb[t * NCOL + c] = (aH0[r] + aH1[r]) + (aL0[r] + aL1[r]);
      }
    }
  }
}

// ---------------- launch --------------------------------------------------------------

extern "C" void kernel_launch(void* const* d_in, const int* in_sizes, int n_in,
                              void* d_out, int out_size, void* d_ws, size_t ws_size,
                              hipStream_t stream) {
  const float* x     = (const float*)d_in[0];   // (256, 36, 50)
  const float* rho   = (const float*)d_in[1];   // (80,)
  const float* theta = (const float*)d_in[2];   // (80,)

  float* out    = (float*)d_out;
  float* outC   = out;                              // 256*161*50
  float* outDic = out + 256 * PDIM * NCOL;          // 36*161
  float* outR   = outDic + TDIM * PDIM;             // 256*36*50

  hipLaunchKernelGGL(dan_kernel, dim3(256), dim3(768), LDS_TOTAL, stream,
                     x, rho, theta, outC, outDic, outR);
}